// Round 1
// baseline (228.819 us; speedup 1.0000x reference)
//
#include <hip/hip_runtime.h>
#include <math.h>

#define C_DIM 384
#define NHEADS 6
#define HD 64
#define BATCH 8
#define NSEQ 1024

// out[M,N] = A[M,K] @ W[N,K]^T (+ bias), all fp32 row-major.
// BM=BN=64, BK=16, 256 threads, 4x4 micro-tile per thread.
template<bool BIAS>
__global__ __launch_bounds__(256) void gemm_nt(
    const float* __restrict__ A, const float* __restrict__ W,
    const float* __restrict__ bias, float* __restrict__ out,
    int M, int N, int K) {
  __shared__ float As[64][17];
  __shared__ float Ws[64][17];

  const int tid = threadIdx.x;
  const int tx = tid & 15;       // 0..15 -> output col group
  const int ty = tid >> 4;       // 0..15 -> output row group
  const int rowBase = blockIdx.y * 64;
  const int colBase = blockIdx.x * 64;

  float acc[4][4] = {};

  for (int k0 = 0; k0 < K; k0 += 16) {
    // Load 64x16 tiles of A and W (4 elements per thread each).
#pragma unroll
    for (int i = 0; i < 4; ++i) {
      int idx = tid + i * 256;          // 0..1023
      int r = idx >> 4;                 // 0..63
      int kk = idx & 15;                // 0..15
      As[r][kk] = A[(size_t)(rowBase + r) * K + k0 + kk];
      Ws[r][kk] = W[(size_t)(colBase + r) * K + k0 + kk];
    }
    __syncthreads();

#pragma unroll
    for (int kk = 0; kk < 16; ++kk) {
      float a[4], w[4];
#pragma unroll
      for (int i = 0; i < 4; ++i) a[i] = As[ty * 4 + i][kk];
#pragma unroll
      for (int j = 0; j < 4; ++j) w[j] = Ws[tx * 4 + j][kk];
#pragma unroll
      for (int i = 0; i < 4; ++i)
#pragma unroll
        for (int j = 0; j < 4; ++j) acc[i][j] += a[i] * w[j];
    }
    __syncthreads();
  }

#pragma unroll
  for (int i = 0; i < 4; ++i) {
    int r = rowBase + ty * 4 + i;
#pragma unroll
    for (int j = 0; j < 4; ++j) {
      int c = colBase + tx * 4 + j;
      float v = acc[i][j];
      if (BIAS) v += bias[c];
      out[(size_t)r * N + c] = v;
    }
  }
}

// One wave (64 lanes = head_dim) per (b, n, h).
// qkv layout: [B, N, 3*C] with q at [h*64+d], k at [C + h*64+d], v at [2C + h*64+d].
__global__ __launch_bounds__(64) void local_attn(
    const float* __restrict__ qkv, float* __restrict__ attn_out) {
  const int bid = blockIdx.x;
  const int h = bid % NHEADS;
  const int n = (bid / NHEADS) % NSEQ;
  const int b = bid / (NHEADS * NSEQ);
  const int d = threadIdx.x;  // 0..63
  const float scale = 0.125f; // 1/sqrt(64)

  const size_t rowStride = 3 * C_DIM;
  const size_t qoff = ((size_t)b * NSEQ + n) * rowStride + h * HD + d;
  const float qd = qkv[qoff];

  float s[3];
  bool valid[3];
  float pmax = -INFINITY;
#pragma unroll
  for (int jj = 0; jj < 3; ++jj) {
    int j = n + jj - 1;
    valid[jj] = (j >= 0 && j < NSEQ);
    if (!valid[jj]) { s[jj] = 0.f; continue; }
    const size_t koff = ((size_t)b * NSEQ + j) * rowStride + C_DIM + h * HD + d;
    float prod = qd * qkv[koff];
    // 64-lane reduction
#pragma unroll
    for (int off = 32; off; off >>= 1) prod += __shfl_xor(prod, off);
    s[jj] = prod * scale;
    pmax = fmaxf(pmax, s[jj]);
  }

  float p[3];
  float denom = 0.f;
#pragma unroll
  for (int jj = 0; jj < 3; ++jj) {
    p[jj] = valid[jj] ? expf(s[jj] - pmax) : 0.f;
    denom += p[jj];
  }
  const float inv = 1.f / denom;

  float od = 0.f;
#pragma unroll
  for (int jj = 0; jj < 3; ++jj) {
    if (!valid[jj]) continue;
    int j = n + jj - 1;
    const size_t voff = ((size_t)b * NSEQ + j) * rowStride + 2 * C_DIM + h * HD + d;
    od += p[jj] * qkv[voff];
  }
  od *= inv;

  attn_out[((size_t)b * NSEQ + n) * C_DIM + h * HD + d] = od;
}

extern "C" void kernel_launch(void* const* d_in, const int* in_sizes, int n_in,
                              void* d_out, int out_size, void* d_ws, size_t ws_size,
                              hipStream_t stream) {
  const float* x      = (const float*)d_in[0];  // [B,N,C]
  const float* qkv_w  = (const float*)d_in[1];  // [3C,C]
  const float* proj_w = (const float*)d_in[2];  // [C,C]
  const float* proj_b = (const float*)d_in[3];  // [C]
  float* out = (float*)d_out;                   // [B,N,C]

  float* qkv  = (float*)d_ws;                                   // [B,N,3C] = 37.75 MB
  float* attn = qkv + (size_t)BATCH * NSEQ * 3 * C_DIM;         // [B,N,C]  = 12.58 MB

  const int M = BATCH * NSEQ;  // 8192

  // 1) qkv = x @ qkv_w^T   [8192, 1152]
  gemm_nt<false><<<dim3((3 * C_DIM) / 64, M / 64), 256, 0, stream>>>(
      x, qkv_w, nullptr, qkv, M, 3 * C_DIM, C_DIM);

  // 2) banded local attention (window 3), merged-head output [B,N,C]
  local_attn<<<BATCH * NSEQ * NHEADS, 64, 0, stream>>>(qkv, attn);

  // 3) out = attn @ proj_w^T + proj_b   [8192, 384]
  gemm_nt<true><<<dim3(C_DIM / 64, M / 64), 256, 0, stream>>>(
      attn, proj_w, proj_b, out, M, C_DIM, C_DIM);
}

// Round 2
// 71.529 us; speedup vs baseline: 3.1990x; 3.1990x over previous
//
#include <hip/hip_runtime.h>
#include <hip/hip_bf16.h>
#include <math.h>

#define C_DIM 384
#define NHEADS 6
#define HD 64
#define BATCH 8
#define NSEQ 1024
#define M_ROWS (BATCH * NSEQ)

typedef __attribute__((ext_vector_type(4))) float f32x4;
typedef __attribute__((ext_vector_type(8))) short s16x8;

__device__ __forceinline__ void gload_lds16(const void* g, void* l) {
  __builtin_amdgcn_global_load_lds(
      (const __attribute__((address_space(1))) unsigned int*)g,
      (__attribute__((address_space(3))) unsigned int*)l, 16, 0, 0);
}

__global__ __launch_bounds__(256) void cast_f32_to_bf16(
    const float* __restrict__ src, __hip_bfloat16* __restrict__ dst, int n4) {
  int idx = blockIdx.x * blockDim.x + threadIdx.x;
  int stride = gridDim.x * blockDim.x;
  for (int i = idx; i < n4; i += stride) {
    float4 v = ((const float4*)src)[i];
    union { ushort4 u; __hip_bfloat16 h[4]; } o;
    o.h[0] = __float2bfloat16(v.x);
    o.h[1] = __float2bfloat16(v.y);
    o.h[2] = __float2bfloat16(v.z);
    o.h[3] = __float2bfloat16(v.w);
    ((ushort4*)dst)[i] = o.u;
  }
}

// out[M,N] = A[M,K] @ W[N,K]^T, bf16 inputs, fp32 accumulate.
// 128x128 tile, BK=32, 256 threads = 4 waves (2x2 of 64x64),
// 16x16x32 bf16 MFMA, global_load_lds width-16 staging (m97 structure).
template<bool OUT_BF16>
__global__ __launch_bounds__(256) void gemm_bf16_nt(
    const __hip_bfloat16* __restrict__ A,  // [M,K]
    const __hip_bfloat16* __restrict__ W,  // [N,K]
    const float* __restrict__ bias,        // [N] (only if !OUT_BF16)
    void* __restrict__ outp,
    int M, int N, int K) {
  __shared__ __align__(16) __hip_bfloat16 As[128 * 32];
  __shared__ __align__(16) __hip_bfloat16 Bs[128 * 32];

  const int tid = threadIdx.x;
  const int lane = tid & 63;
  const int wave = tid >> 6;
  const int wr = (wave >> 1) * 64;   // wave row offset in tile
  const int wc = (wave & 1) * 64;    // wave col offset in tile
  const int rowBase = blockIdx.y * 128;
  const int colBase = blockIdx.x * 128;

  const int l16 = lane & 15;
  const int lk8 = (lane >> 4) * 8;   // K offset for A/B fragments
  const int lr4 = (lane >> 4) * 4;   // row offset for C/D fragments

  f32x4 acc[4][4] = {};

  const int nkt = K >> 5;
  for (int kt = 0; kt < nkt; ++kt) {
    const int k0 = kt * 32;
    // Stage A-tile [128][32] and B-tile [128][32] (bf16) into LDS.
    // 512 chunks of 16B each; 256 threads x 2 chunks. LDS dest is linear
    // (base + lane*16) as global_load_lds requires.
#pragma unroll
    for (int i = 0; i < 2; ++i) {
      int c = tid + i * 256;
      int r = c >> 2;
      int cc = (c & 3) * 8;
      gload_lds16(A + (size_t)(rowBase + r) * K + k0 + cc, As + c * 8);
      gload_lds16(W + (size_t)(colBase + r) * K + k0 + cc, Bs + c * 8);
    }
    __syncthreads();

    s16x8 af[4], bf[4];
#pragma unroll
    for (int m = 0; m < 4; ++m)
      af[m] = *(const s16x8*)(As + (wr + m * 16 + l16) * 32 + lk8);
#pragma unroll
    for (int n = 0; n < 4; ++n)
      bf[n] = *(const s16x8*)(Bs + (wc + n * 16 + l16) * 32 + lk8);
#pragma unroll
    for (int m = 0; m < 4; ++m)
#pragma unroll
      for (int n = 0; n < 4; ++n)
        acc[m][n] = __builtin_amdgcn_mfma_f32_16x16x32_bf16(
            af[m], bf[n], acc[m][n], 0, 0, 0);
    __syncthreads();
  }

  // Epilogue. C/D layout: col = lane&15, row = (lane>>4)*4 + j (m89-verified).
#pragma unroll
  for (int m = 0; m < 4; ++m) {
    int rb = rowBase + wr + m * 16 + lr4;
#pragma unroll
    for (int n = 0; n < 4; ++n) {
      int cb = colBase + wc + n * 16 + l16;
#pragma unroll
      for (int j = 0; j < 4; ++j) {
        float v = acc[m][n][j];
        if (OUT_BF16) {
          ((__hip_bfloat16*)outp)[(size_t)(rb + j) * N + cb] = __float2bfloat16(v);
        } else {
          ((float*)outp)[(size_t)(rb + j) * N + cb] = v + bias[cb];
        }
      }
    }
  }
}

// One wave per (b, n, h); lane = head dim. Window-3 banded softmax-AV.
__global__ __launch_bounds__(64) void local_attn_bf16(
    const __hip_bfloat16* __restrict__ qkv, __hip_bfloat16* __restrict__ attn_out) {
  const int bid = blockIdx.x;
  const int h = bid % NHEADS;
  const int n = (bid / NHEADS) % NSEQ;
  const int b = bid / (NHEADS * NSEQ);
  const int d = threadIdx.x;
  const float scale = 0.125f;  // 1/sqrt(64)

  const size_t rowStride = 3 * C_DIM;
  const float qd = __bfloat162float(qkv[((size_t)b * NSEQ + n) * rowStride + h * HD + d]);

  float s[3];
  bool valid[3];
  float pmax = -INFINITY;
#pragma unroll
  for (int jj = 0; jj < 3; ++jj) {
    int j = n + jj - 1;
    valid[jj] = (j >= 0 && j < NSEQ);
    if (!valid[jj]) { s[jj] = 0.f; continue; }
    float kd = __bfloat162float(qkv[((size_t)b * NSEQ + j) * rowStride + C_DIM + h * HD + d]);
    float prod = qd * kd;
#pragma unroll
    for (int off = 32; off; off >>= 1) prod += __shfl_xor(prod, off);
    s[jj] = prod * scale;
    pmax = fmaxf(pmax, s[jj]);
  }

  float p[3];
  float denom = 0.f;
#pragma unroll
  for (int jj = 0; jj < 3; ++jj) {
    p[jj] = valid[jj] ? expf(s[jj] - pmax) : 0.f;
    denom += p[jj];
  }
  const float inv = 1.f / denom;

  float od = 0.f;
#pragma unroll
  for (int jj = 0; jj < 3; ++jj) {
    if (!valid[jj]) continue;
    int j = n + jj - 1;
    od += p[jj] * __bfloat162float(
        qkv[((size_t)b * NSEQ + j) * rowStride + 2 * C_DIM + h * HD + d]);
  }
  od *= inv;

  attn_out[((size_t)b * NSEQ + n) * C_DIM + h * HD + d] = __float2bfloat16(od);
}

extern "C" void kernel_launch(void* const* d_in, const int* in_sizes, int n_in,
                              void* d_out, int out_size, void* d_ws, size_t ws_size,
                              hipStream_t stream) {
  const float* x      = (const float*)d_in[0];  // [B,N,C]
  const float* qkv_w  = (const float*)d_in[1];  // [3C,C]
  const float* proj_w = (const float*)d_in[2];  // [C,C]
  const float* proj_b = (const float*)d_in[3];  // [C]
  float* out = (float*)d_out;                   // [B,N,C] fp32

  __hip_bfloat16* x_bf     = (__hip_bfloat16*)d_ws;                       // 3,145,728
  __hip_bfloat16* qkvw_bf  = x_bf + (size_t)M_ROWS * C_DIM;               // 442,368
  __hip_bfloat16* projw_bf = qkvw_bf + (size_t)3 * C_DIM * C_DIM;         // 147,456
  __hip_bfloat16* qkv_bf   = projw_bf + (size_t)C_DIM * C_DIM;            // 9,437,184
  __hip_bfloat16* attn_bf  = qkv_bf + (size_t)M_ROWS * 3 * C_DIM;         // 3,145,728

  // 1) casts to bf16
  cast_f32_to_bf16<<<1024, 256, 0, stream>>>(x, x_bf, M_ROWS * C_DIM / 4);
  cast_f32_to_bf16<<<128, 256, 0, stream>>>(qkv_w, qkvw_bf, 3 * C_DIM * C_DIM / 4);
  cast_f32_to_bf16<<<64, 256, 0, stream>>>(proj_w, projw_bf, C_DIM * C_DIM / 4);

  // 2) qkv = x @ qkv_w^T  [8192, 1152] bf16
  gemm_bf16_nt<true><<<dim3((3 * C_DIM) / 128, M_ROWS / 128), 256, 0, stream>>>(
      x_bf, qkvw_bf, nullptr, qkv_bf, M_ROWS, 3 * C_DIM, C_DIM);

  // 3) banded local attention (window 3) -> [B,N,C] bf16
  local_attn_bf16<<<BATCH * NSEQ * NHEADS, 64, 0, stream>>>(qkv_bf, attn_bf);

  // 4) out = attn @ proj_w^T + proj_b  [8192, 384] fp32
  gemm_bf16_nt<false><<<dim3(C_DIM / 128, M_ROWS / 128), 256, 0, stream>>>(
      attn_bf, projw_bf, proj_b, out, M_ROWS, C_DIM, C_DIM);
}

// Round 3
// 54.607 us; speedup vs baseline: 4.1903x; 1.3099x over previous
//
#include <hip/hip_runtime.h>
#include <hip/hip_bf16.h>
#include <math.h>

#define C_DIM 384
#define NHEADS 6
#define HD 64
#define BATCH 8
#define NSEQ 1024
#define M_ROWS (BATCH * NSEQ)

typedef __attribute__((ext_vector_type(4))) float f32x4;
typedef __attribute__((ext_vector_type(8))) short s16x8;

__device__ __forceinline__ float bf2f(short u) {
  return __uint_as_float(((unsigned)(unsigned short)u) << 16);
}
__device__ __forceinline__ short f2bf(float f) {
  __hip_bfloat16 h = __float2bfloat16(f);
  return *reinterpret_cast<short*>(&h);
}

__device__ __forceinline__ void gload_lds16(const void* g, void* l) {
  __builtin_amdgcn_global_load_lds(
      (const __attribute__((address_space(1))) unsigned int*)g,
      (__attribute__((address_space(3))) unsigned int*)l, 16, 0, 0);
}

// Single fused cast: x, qkv_w, proj_w  fp32 -> bf16, 4 elems per iter.
__global__ __launch_bounds__(256) void cast_all(
    const float* __restrict__ x, const float* __restrict__ qw,
    const float* __restrict__ pw,
    ushort4* __restrict__ xo, ushort4* __restrict__ qo, ushort4* __restrict__ po) {
  const int NX = M_ROWS * C_DIM / 4;
  const int NQ = 3 * C_DIM * C_DIM / 4;
  const int NP = C_DIM * C_DIM / 4;
  const int total = NX + NQ + NP;
  int idx = blockIdx.x * blockDim.x + threadIdx.x;
  int stride = gridDim.x * blockDim.x;
  for (int i = idx; i < total; i += stride) {
    const float4* s;
    ushort4* d;
    int off;
    if (i < NX) { s = (const float4*)x; d = xo; off = i; }
    else if (i < NX + NQ) { s = (const float4*)qw; d = qo; off = i - NX; }
    else { s = (const float4*)pw; d = po; off = i - NX - NQ; }
    float4 v = s[off];
    ushort4 o;
    o.x = (unsigned short)f2bf(v.x);
    o.y = (unsigned short)f2bf(v.y);
    o.z = (unsigned short)f2bf(v.z);
    o.w = (unsigned short)f2bf(v.w);
    d[off] = o;
  }
}

// out[M,N] = A[M,K] @ W[N,K]^T, bf16 in, fp32 acc. 128x128 tile, BK=32,
// 4 waves (2x2 of 64x64), 16x16x32 MFMA, global_load_lds staging.
template<bool OUT_BF16>
__global__ __launch_bounds__(256) void gemm_bf16_nt(
    const __hip_bfloat16* __restrict__ A,
    const __hip_bfloat16* __restrict__ W,
    const float* __restrict__ bias,
    void* __restrict__ outp,
    int M, int N, int K) {
  __shared__ __align__(16) __hip_bfloat16 As[128 * 32];
  __shared__ __align__(16) __hip_bfloat16 Bs[128 * 32];

  const int tid = threadIdx.x;
  const int lane = tid & 63;
  const int wave = tid >> 6;
  const int wr = (wave >> 1) * 64;
  const int wc = (wave & 1) * 64;
  const int rowBase = blockIdx.y * 128;
  const int colBase = blockIdx.x * 128;

  const int l16 = lane & 15;
  const int lk8 = (lane >> 4) * 8;
  const int lr4 = (lane >> 4) * 4;

  f32x4 acc[4][4] = {};

  const int nkt = K >> 5;
  for (int kt = 0; kt < nkt; ++kt) {
    const int k0 = kt * 32;
#pragma unroll
    for (int i = 0; i < 2; ++i) {
      int c = tid + i * 256;
      int r = c >> 2;
      int cc = (c & 3) * 8;
      gload_lds16(A + (size_t)(rowBase + r) * K + k0 + cc, As + c * 8);
      gload_lds16(W + (size_t)(colBase + r) * K + k0 + cc, Bs + c * 8);
    }
    __syncthreads();

    s16x8 af[4], bf[4];
#pragma unroll
    for (int m = 0; m < 4; ++m)
      af[m] = *(const s16x8*)(As + (wr + m * 16 + l16) * 32 + lk8);
#pragma unroll
    for (int n = 0; n < 4; ++n)
      bf[n] = *(const s16x8*)(Bs + (wc + n * 16 + l16) * 32 + lk8);
#pragma unroll
    for (int m = 0; m < 4; ++m)
#pragma unroll
      for (int n = 0; n < 4; ++n)
        acc[m][n] = __builtin_amdgcn_mfma_f32_16x16x32_bf16(
            af[m], bf[n], acc[m][n], 0, 0, 0);
    __syncthreads();
  }

#pragma unroll
  for (int m = 0; m < 4; ++m) {
    int rb = rowBase + wr + m * 16 + lr4;
#pragma unroll
    for (int n = 0; n < 4; ++n) {
      int cb = colBase + wc + n * 16 + l16;
#pragma unroll
      for (int j = 0; j < 4; ++j) {
        float v = acc[m][n][j];
        if (OUT_BF16) {
          ((__hip_bfloat16*)outp)[(size_t)(rb + j) * N + cb] = __float2bfloat16(v);
        } else {
          ((float*)outp)[(size_t)(rb + j) * N + cb] = v + bias[cb];
        }
      }
    }
  }
}

// One THREAD per (b, n, h). Fully vectorized 16B loads, no cross-lane ops.
// Window-3 banded softmax + AV, all in registers.
__global__ __launch_bounds__(256) void local_attn_v2(
    const __hip_bfloat16* __restrict__ qkv, __hip_bfloat16* __restrict__ attn_out) {
  const int t = blockIdx.x * 256 + threadIdx.x;
  const int h = t % NHEADS;
  const int n = (t / NHEADS) % NSEQ;
  const int b = t / (NHEADS * NSEQ);
  const size_t RS = 3 * C_DIM;
  const size_t rowQ = ((size_t)b * NSEQ + n) * RS;

  // q row -> 64 fp32 registers
  float qf[64];
  {
    const s16x8* qp = (const s16x8*)(qkv + rowQ + h * HD);
#pragma unroll
    for (int c = 0; c < 8; ++c) {
      s16x8 v = qp[c];
#pragma unroll
      for (int e = 0; e < 8; ++e) qf[c * 8 + e] = bf2f(v[e]);
    }
  }

  // scores for j = n-1, n, n+1
  float s[3];
#pragma unroll
  for (int jj = 0; jj < 3; ++jj) {
    int j = n + jj - 1;
    if ((unsigned)j < NSEQ) {
      const s16x8* kp = (const s16x8*)(qkv + ((size_t)b * NSEQ + j) * RS + C_DIM + h * HD);
      float a0 = 0.f, a1 = 0.f, a2 = 0.f, a3 = 0.f;
#pragma unroll
      for (int c = 0; c < 8; ++c) {
        s16x8 v = kp[c];
        a0 += qf[c * 8 + 0] * bf2f(v[0]);
        a1 += qf[c * 8 + 1] * bf2f(v[1]);
        a2 += qf[c * 8 + 2] * bf2f(v[2]);
        a3 += qf[c * 8 + 3] * bf2f(v[3]);
        a0 += qf[c * 8 + 4] * bf2f(v[4]);
        a1 += qf[c * 8 + 5] * bf2f(v[5]);
        a2 += qf[c * 8 + 6] * bf2f(v[6]);
        a3 += qf[c * 8 + 7] * bf2f(v[7]);
      }
      s[jj] = (a0 + a1 + a2 + a3) * 0.125f;
    } else {
      s[jj] = -1e30f;
    }
  }
  float mx = fmaxf(s[0], fmaxf(s[1], s[2]));
  float p0 = __expf(s[0] - mx);
  float p1 = __expf(s[1] - mx);
  float p2 = __expf(s[2] - mx);
  float inv = 1.f / (p0 + p1 + p2);
  p0 *= inv; p1 *= inv; p2 *= inv;

  // AV: out = p0*v[n-1] + p1*v[n] + p2*v[n+1]  (clamped rows carry p==0)
  int jm = n > 0 ? n - 1 : 0;
  int jp = n < NSEQ - 1 ? n + 1 : NSEQ - 1;
  const s16x8* vm = (const s16x8*)(qkv + ((size_t)b * NSEQ + jm) * RS + 2 * C_DIM + h * HD);
  const s16x8* vc = (const s16x8*)(qkv + rowQ + 2 * C_DIM + h * HD);
  const s16x8* vp = (const s16x8*)(qkv + ((size_t)b * NSEQ + jp) * RS + 2 * C_DIM + h * HD);
  s16x8* op = (s16x8*)(attn_out + ((size_t)b * NSEQ + n) * C_DIM + h * HD);
#pragma unroll
  for (int c = 0; c < 8; ++c) {
    s16x8 va = vm[c], vb = vc[c], vcx = vp[c];
    s16x8 o;
#pragma unroll
    for (int e = 0; e < 8; ++e) {
      float r = p0 * bf2f(va[e]) + p1 * bf2f(vb[e]) + p2 * bf2f(vcx[e]);
      o[e] = f2bf(r);
    }
    op[c] = o;
  }
}

extern "C" void kernel_launch(void* const* d_in, const int* in_sizes, int n_in,
                              void* d_out, int out_size, void* d_ws, size_t ws_size,
                              hipStream_t stream) {
  const float* x      = (const float*)d_in[0];  // [B,N,C]
  const float* qkv_w  = (const float*)d_in[1];  // [3C,C]
  const float* proj_w = (const float*)d_in[2];  // [C,C]
  const float* proj_b = (const float*)d_in[3];  // [C]
  float* out = (float*)d_out;                   // [B,N,C] fp32

  __hip_bfloat16* x_bf     = (__hip_bfloat16*)d_ws;
  __hip_bfloat16* qkvw_bf  = x_bf + (size_t)M_ROWS * C_DIM;
  __hip_bfloat16* projw_bf = qkvw_bf + (size_t)3 * C_DIM * C_DIM;
  __hip_bfloat16* qkv_bf   = projw_bf + (size_t)C_DIM * C_DIM;
  __hip_bfloat16* attn_bf  = qkv_bf + (size_t)M_ROWS * 3 * C_DIM;

  // 1) fused casts to bf16 (one kernel)
  cast_all<<<1024, 256, 0, stream>>>(
      x, qkv_w, proj_w, (ushort4*)x_bf, (ushort4*)qkvw_bf, (ushort4*)projw_bf);

  // 2) qkv = x @ qkv_w^T  [8192, 1152] bf16
  gemm_bf16_nt<true><<<dim3((3 * C_DIM) / 128, M_ROWS / 128), 256, 0, stream>>>(
      x_bf, qkvw_bf, nullptr, qkv_bf, M_ROWS, 3 * C_DIM, C_DIM);

  // 3) banded local attention (window 3), one thread per (b,n,h)
  local_attn_v2<<<(M_ROWS * NHEADS) / 256, 256, 0, stream>>>(qkv_bf, attn_bf);

  // 4) out = attn @ proj_w^T + proj_b  [8192, 384] fp32
  gemm_bf16_nt<false><<<dim3(C_DIM / 128, M_ROWS / 128), 256, 0, stream>>>(
      attn_bf, projw_bf, proj_b, out, M_ROWS, C_DIM, C_DIM);
}

// Round 4
// 50.209 us; speedup vs baseline: 4.5573x; 1.0876x over previous
//
#include <hip/hip_runtime.h>
#include <hip/hip_bf16.h>
#include <math.h>

#define C_DIM 384
#define NHEADS 6
#define HD 64
#define BATCH 8
#define NSEQ 1024
#define M_ROWS (BATCH * NSEQ)

typedef __attribute__((ext_vector_type(4))) float f32x4;
typedef __attribute__((ext_vector_type(8))) short s16x8;

__device__ __forceinline__ float bf2f(short u) {
  return __uint_as_float(((unsigned)(unsigned short)u) << 16);
}
__device__ __forceinline__ short f2bf(float f) {
  __hip_bfloat16 h = __float2bfloat16(f);
  return *reinterpret_cast<short*>(&h);
}

__device__ __forceinline__ void gload_lds16(const void* g, void* l) {
  __builtin_amdgcn_global_load_lds(
      (const __attribute__((address_space(1))) unsigned int*)g,
      (__attribute__((address_space(3))) unsigned int*)l, 16, 0, 0);
}

// Single fused cast: x, qkv_w, proj_w  fp32 -> bf16, 4 elems per iter.
__global__ __launch_bounds__(256) void cast_all(
    const float* __restrict__ x, const float* __restrict__ qw,
    const float* __restrict__ pw,
    ushort4* __restrict__ xo, ushort4* __restrict__ qo, ushort4* __restrict__ po) {
  const int NX = M_ROWS * C_DIM / 4;
  const int NQ = 3 * C_DIM * C_DIM / 4;
  const int NP = C_DIM * C_DIM / 4;
  const int total = NX + NQ + NP;
  int idx = blockIdx.x * blockDim.x + threadIdx.x;
  int stride = gridDim.x * blockDim.x;
  for (int i = idx; i < total; i += stride) {
    const float4* s;
    ushort4* d;
    int off;
    if (i < NX) { s = (const float4*)x; d = xo; off = i; }
    else if (i < NX + NQ) { s = (const float4*)qw; d = qo; off = i - NX; }
    else { s = (const float4*)pw; d = po; off = i - NX - NQ; }
    float4 v = s[off];
    ushort4 o;
    o.x = (unsigned short)f2bf(v.x);
    o.y = (unsigned short)f2bf(v.y);
    o.z = (unsigned short)f2bf(v.z);
    o.w = (unsigned short)f2bf(v.w);
    d[off] = o;
  }
}

// out[M,N] = A[M,K] @ W[N,K]^T, bf16 in, fp32 acc. 128x128 tile, BK=32,
// 4 waves (2x2 of 64x64), 16x16x32 MFMA, global_load_lds staging.
template<bool OUT_BF16>
__global__ __launch_bounds__(256) void gemm_bf16_nt(
    const __hip_bfloat16* __restrict__ A,
    const __hip_bfloat16* __restrict__ W,
    const float* __restrict__ bias,
    void* __restrict__ outp,
    int M, int N, int K) {
  __shared__ __align__(16) __hip_bfloat16 As[128 * 32];
  __shared__ __align__(16) __hip_bfloat16 Bs[128 * 32];

  const int tid = threadIdx.x;
  const int lane = tid & 63;
  const int wave = tid >> 6;
  const int wr = (wave >> 1) * 64;
  const int wc = (wave & 1) * 64;
  const int rowBase = blockIdx.y * 128;
  const int colBase = blockIdx.x * 128;

  const int l16 = lane & 15;
  const int lk8 = (lane >> 4) * 8;
  const int lr4 = (lane >> 4) * 4;

  f32x4 acc[4][4] = {};

  const int nkt = K >> 5;
  for (int kt = 0; kt < nkt; ++kt) {
    const int k0 = kt * 32;
#pragma unroll
    for (int i = 0; i < 2; ++i) {
      int c = tid + i * 256;
      int r = c >> 2;
      int cc = (c & 3) * 8;
      gload_lds16(A + (size_t)(rowBase + r) * K + k0 + cc, As + c * 8);
      gload_lds16(W + (size_t)(colBase + r) * K + k0 + cc, Bs + c * 8);
    }
    __syncthreads();

    s16x8 af[4], bf[4];
#pragma unroll
    for (int m = 0; m < 4; ++m)
      af[m] = *(const s16x8*)(As + (wr + m * 16 + l16) * 32 + lk8);
#pragma unroll
    for (int n = 0; n < 4; ++n)
      bf[n] = *(const s16x8*)(Bs + (wc + n * 16 + l16) * 32 + lk8);
#pragma unroll
    for (int m = 0; m < 4; ++m)
#pragma unroll
      for (int n = 0; n < 4; ++n)
        acc[m][n] = __builtin_amdgcn_mfma_f32_16x16x32_bf16(
            af[m], bf[n], acc[m][n], 0, 0, 0);
    __syncthreads();
  }

#pragma unroll
  for (int m = 0; m < 4; ++m) {
    int rb = rowBase + wr + m * 16 + lr4;
#pragma unroll
    for (int n = 0; n < 4; ++n) {
      int cb = colBase + wc + n * 16 + l16;
#pragma unroll
      for (int j = 0; j < 4; ++j) {
        float v = acc[m][n][j];
        if (OUT_BF16) {
          ((__hip_bfloat16*)outp)[(size_t)(rb + j) * N + cb] = __float2bfloat16(v);
        } else {
          ((float*)outp)[(size_t)(rb + j) * N + cb] = v + bias[cb];
        }
      }
    }
  }
}

// Local attention v3: one block per (128-row panel, head).
// Coalesced global_load_lds staging of q/k/v head-slices into LDS with
// XOR-swizzled SOURCE addressing (linear LDS dest); 2 threads per row.
__global__ __launch_bounds__(256) void local_attn_v3(
    const __hip_bfloat16* __restrict__ qkv, __hip_bfloat16* __restrict__ attn_out) {
  // Q: 128 rows x 8 chunks; K,V: 130 rows x 8 chunks (16B chunks)
  __shared__ __align__(16) ushort lds[24832];
  const int QOFF = 0;
  const int KOFF = 8192;          // 1024 chunks * 8 ushorts
  const int VOFF = 8192 + 8320;   // +1040 chunks * 8

  const int tid = threadIdx.x;
  const int mb = blockIdx.x & 63;
  const int h  = blockIdx.x >> 6;        // 0..5
  const int rb = mb * 128;               // global row base
  const int b  = rb >> 10;
  const int n0 = rb & 1023;
  const int RS = 3 * C_DIM;              // 1152

  // --- stage q: rows rb..rb+127, head slice [h*64, h*64+64) ---
#pragma unroll
  for (int i = 0; i < 4; ++i) {
    int s = i * 256 + tid;
    int r = s >> 3;
    int jg = (s & 7) ^ (r & 7);          // source pre-swizzle (involution)
    gload_lds16(qkv + (size_t)(rb + r) * RS + h * HD + jg * 8,
                lds + QOFF + s * 8);
  }
  // --- stage k, v: rows rb-1..rb+128 clamped within batch ---
#pragma unroll
  for (int i = 0; i < 5; ++i) {
    int s = i * 256 + tid;
    if (s < 1040) {
      int r = s >> 3;                    // 0..129
      int jg = (s & 7) ^ (r & 7);
      int nl = n0 + r - 1;
      nl = nl < 0 ? 0 : (nl > 1023 ? 1023 : nl);
      size_t row = (size_t)(b << 10) + nl;
      gload_lds16(qkv + row * RS + C_DIM + h * HD + jg * 8, lds + KOFF + s * 8);
      gload_lds16(qkv + row * RS + 2 * C_DIM + h * HD + jg * 8, lds + VOFF + s * 8);
    }
  }
  __syncthreads();

  // --- phase 2: task = (row r, half of head-dim) ---
  const int r = tid >> 1;
  const int half = tid & 1;
  const int jbase = half * 4;
  const int n = n0 + r;

  float qf[32];
#pragma unroll
  for (int c = 0; c < 4; ++c) {
    int slot = r * 8 + ((jbase + c) ^ (r & 7));
    s16x8 v = *(const s16x8*)(lds + QOFF + slot * 8);
#pragma unroll
    for (int e = 0; e < 8; ++e) qf[c * 8 + e] = bf2f(v[e]);
  }

  float s3[3];
#pragma unroll
  for (int jj = 0; jj < 3; ++jj) {
    int krow = r + jj;                   // LDS row = j_local + 1
    float acc = 0.f;
#pragma unroll
    for (int c = 0; c < 4; ++c) {
      int slot = krow * 8 + ((jbase + c) ^ (krow & 7));
      s16x8 v = *(const s16x8*)(lds + KOFF + slot * 8);
#pragma unroll
      for (int e = 0; e < 8; ++e) acc += qf[c * 8 + e] * bf2f(v[e]);
    }
    acc += __shfl_xor(acc, 1);           // pair-combine the two halves
    s3[jj] = ((unsigned)(n + jj - 1) < (unsigned)NSEQ) ? acc * 0.125f : -1e30f;
  }

  float mx = fmaxf(s3[0], fmaxf(s3[1], s3[2]));
  float p0 = __expf(s3[0] - mx);
  float p1 = __expf(s3[1] - mx);
  float p2 = __expf(s3[2] - mx);
  float inv = 1.f / (p0 + p1 + p2);
  float p[3] = {p0 * inv, p1 * inv, p2 * inv};

  float of[32] = {};
#pragma unroll
  for (int jj = 0; jj < 3; ++jj) {
    int krow = r + jj;
    float pw = p[jj];
#pragma unroll
    for (int c = 0; c < 4; ++c) {
      int slot = krow * 8 + ((jbase + c) ^ (krow & 7));
      s16x8 v = *(const s16x8*)(lds + VOFF + slot * 8);
#pragma unroll
      for (int e = 0; e < 8; ++e) of[c * 8 + e] += pw * bf2f(v[e]);
    }
  }

#pragma unroll
  for (int c = 0; c < 4; ++c) {
    s16x8 o;
#pragma unroll
    for (int e = 0; e < 8; ++e) o[e] = f2bf(of[c * 8 + e]);
    *(s16x8*)(attn_out + (size_t)(rb + r) * C_DIM + h * HD + jbase * 8 + c * 8) = o;
  }
}

extern "C" void kernel_launch(void* const* d_in, const int* in_sizes, int n_in,
                              void* d_out, int out_size, void* d_ws, size_t ws_size,
                              hipStream_t stream) {
  const float* x      = (const float*)d_in[0];  // [B,N,C]
  const float* qkv_w  = (const float*)d_in[1];  // [3C,C]
  const float* proj_w = (const float*)d_in[2];  // [C,C]
  const float* proj_b = (const float*)d_in[3];  // [C]
  float* out = (float*)d_out;                   // [B,N,C] fp32

  __hip_bfloat16* x_bf     = (__hip_bfloat16*)d_ws;
  __hip_bfloat16* qkvw_bf  = x_bf + (size_t)M_ROWS * C_DIM;
  __hip_bfloat16* projw_bf = qkvw_bf + (size_t)3 * C_DIM * C_DIM;
  __hip_bfloat16* qkv_bf   = projw_bf + (size_t)C_DIM * C_DIM;
  __hip_bfloat16* attn_bf  = qkv_bf + (size_t)M_ROWS * 3 * C_DIM;

  // 1) fused casts to bf16 (one kernel)
  cast_all<<<1024, 256, 0, stream>>>(
      x, qkv_w, proj_w, (ushort4*)x_bf, (ushort4*)qkvw_bf, (ushort4*)projw_bf);

  // 2) qkv = x @ qkv_w^T  [8192, 1152] bf16
  gemm_bf16_nt<true><<<dim3((3 * C_DIM) / 128, M_ROWS / 128), 256, 0, stream>>>(
      x_bf, qkvw_bf, nullptr, qkv_bf, M_ROWS, 3 * C_DIM, C_DIM);

  // 3) banded local attention (window 3): 64 row-panels x 6 heads
  local_attn_v3<<<64 * NHEADS, 256, 0, stream>>>(qkv_bf, attn_bf);

  // 4) out = attn @ proj_w^T + proj_b  [8192, 384] fp32
  gemm_bf16_nt<false><<<dim3(C_DIM / 128, M_ROWS / 128), 256, 0, stream>>>(
      attn_bf, projw_bf, proj_b, out, M_ROWS, C_DIM, C_DIM);
}

// Round 5
// 43.981 us; speedup vs baseline: 5.2026x; 1.1416x over previous
//
#include <hip/hip_runtime.h>
#include <hip/hip_bf16.h>
#include <math.h>

#define C_DIM 384
#define NHEADS 6
#define HD 64
#define BATCH 8
#define NSEQ 1024
#define M_ROWS (BATCH * NSEQ)

typedef __attribute__((ext_vector_type(4))) float f32x4;
typedef __attribute__((ext_vector_type(8))) short s16x8;

__device__ __forceinline__ float bf2f(short u) {
  return __uint_as_float(((unsigned)(unsigned short)u) << 16);
}
__device__ __forceinline__ short f2bf(float f) {
  __hip_bfloat16 h = __float2bfloat16(f);
  return *reinterpret_cast<short*>(&h);
}

__device__ __forceinline__ void gload_lds16(const void* g, void* l) {
  __builtin_amdgcn_global_load_lds(
      (const __attribute__((address_space(1))) unsigned int*)g,
      (__attribute__((address_space(3))) unsigned int*)l, 16, 0, 0);
}

template<int N> __device__ __forceinline__ void wait_vm() {
  if constexpr (N == 0) asm volatile("s_waitcnt vmcnt(0)" ::: "memory");
  else if constexpr (N == 3) asm volatile("s_waitcnt vmcnt(3)" ::: "memory");
  else if constexpr (N == 4) asm volatile("s_waitcnt vmcnt(4)" ::: "memory");
}

// Single fused cast: x, qkv_w, proj_w  fp32 -> bf16.
__global__ __launch_bounds__(256) void cast_all(
    const float* __restrict__ x, const float* __restrict__ qw,
    const float* __restrict__ pw,
    ushort4* __restrict__ xo, ushort4* __restrict__ qo, ushort4* __restrict__ po) {
  const int NX = M_ROWS * C_DIM / 4;
  const int NQ = 3 * C_DIM * C_DIM / 4;
  const int NP = C_DIM * C_DIM / 4;
  const int total = NX + NQ + NP;
  int idx = blockIdx.x * blockDim.x + threadIdx.x;
  int stride = gridDim.x * blockDim.x;
  for (int i = idx; i < total; i += stride) {
    const float4* s;
    ushort4* d;
    int off;
    if (i < NX) { s = (const float4*)x; d = xo; off = i; }
    else if (i < NX + NQ) { s = (const float4*)qw; d = qo; off = i - NX; }
    else { s = (const float4*)pw; d = po; off = i - NX - NQ; }
    float4 v = s[off];
    ushort4 o;
    o.x = (unsigned short)f2bf(v.x);
    o.y = (unsigned short)f2bf(v.y);
    o.z = (unsigned short)f2bf(v.z);
    o.w = (unsigned short)f2bf(v.w);
    d[off] = o;
  }
}

// out[M,N] = A[M,K] @ W[N,K]^T, bf16 in, fp32 acc.
// BM=128, BK=32, BN template (128 or 64). 4 waves (2x2).
// Double-buffered LDS, counted-vmcnt 2-phase pipeline (T3/T4), raw barriers.
template<int BN, bool OUT_BF16>
__global__ __launch_bounds__(256) void gemm_db(
    const __hip_bfloat16* __restrict__ A,
    const __hip_bfloat16* __restrict__ W,
    const float* __restrict__ bias,
    void* __restrict__ outp,
    int M, int N, int K) {
  constexpr int NF = BN / 32;               // n-frags per wave (4 or 2)
  constexpr int BPT = (BN * 32 / 8) / 256;  // B 16B-chunks per thread (2 or 1)
  constexpr int LPS = 2 + BPT;              // gload_lds per thread per stage
  __shared__ __align__(16) __hip_bfloat16 As[2][128 * 32];
  __shared__ __align__(16) __hip_bfloat16 Bs[2][BN * 32];

  const int tid = threadIdx.x;
  // Bijective XCD-aware swizzle (nwg % 8 == 0 for both call sites).
  const int nwg = gridDim.x * gridDim.y;
  const int bid0 = blockIdx.y * gridDim.x + blockIdx.x;
  const int cpx = nwg >> 3;
  const int wg = (bid0 & 7) * cpx + (bid0 >> 3);
  const int bx = wg % gridDim.x;
  const int by = wg / gridDim.x;

  const int lane = tid & 63;
  const int wave = tid >> 6;
  const int wr = (wave >> 1) * 64;
  const int wc = (wave & 1) * (BN / 2);
  const int rowBase = by * 128;
  const int colBase = bx * BN;

  const int l16 = lane & 15;
  const int lk8 = (lane >> 4) * 8;
  const int lr4 = (lane >> 4) * 4;

  f32x4 acc[4][NF] = {};

  const int nkt = K >> 5;

  auto stage = [&](int buf, int kt) {
    const int k0 = kt * 32;
#pragma unroll
    for (int i = 0; i < 2; ++i) {
      int c = tid + i * 256;
      int r = c >> 2, cc = (c & 3) * 8;
      gload_lds16(A + (size_t)(rowBase + r) * K + k0 + cc, &As[buf][c * 8]);
    }
#pragma unroll
    for (int i = 0; i < BPT; ++i) {
      int c = tid + i * 256;
      int r = c >> 2, cc = (c & 3) * 8;
      gload_lds16(W + (size_t)(colBase + r) * K + k0 + cc, &Bs[buf][c * 8]);
    }
  };

  stage(0, 0);
  for (int kt = 0; kt < nkt; ++kt) {
    const int cur = kt & 1;
    if (kt + 1 < nkt) {
      stage(cur ^ 1, kt + 1);   // next tile's loads stay in flight across barrier
      wait_vm<LPS>();           // current tile's loads retired
    } else {
      wait_vm<0>();
    }
    __builtin_amdgcn_sched_barrier(0);
    __builtin_amdgcn_s_barrier();
    __builtin_amdgcn_sched_barrier(0);

    s16x8 af[4], bfr[NF];
#pragma unroll
    for (int m = 0; m < 4; ++m)
      af[m] = *(const s16x8*)(&As[cur][(wr + m * 16 + l16) * 32 + lk8]);
#pragma unroll
    for (int n = 0; n < NF; ++n)
      bfr[n] = *(const s16x8*)(&Bs[cur][(wc + n * 16 + l16) * 32 + lk8]);
#pragma unroll
    for (int m = 0; m < 4; ++m)
#pragma unroll
      for (int n = 0; n < NF; ++n)
        acc[m][n] = __builtin_amdgcn_mfma_f32_16x16x32_bf16(
            af[m], bfr[n], acc[m][n], 0, 0, 0);

    // reads of buf[cur] complete (MFMA lgkm deps) -> safe to overwrite next iter
    __builtin_amdgcn_sched_barrier(0);
    __builtin_amdgcn_s_barrier();
    __builtin_amdgcn_sched_barrier(0);
  }

#pragma unroll
  for (int m = 0; m < 4; ++m) {
    int rb = rowBase + wr + m * 16 + lr4;
#pragma unroll
    for (int n = 0; n < NF; ++n) {
      int cb = colBase + wc + n * 16 + l16;
#pragma unroll
      for (int j = 0; j < 4; ++j) {
        float v = acc[m][n][j];
        if (OUT_BF16) {
          ((__hip_bfloat16*)outp)[(size_t)(rb + j) * N + cb] = __float2bfloat16(v);
        } else {
          ((float*)outp)[(size_t)(rb + j) * N + cb] = v + bias[cb];
        }
      }
    }
  }
}

// Local attention: one block per (128-row panel, head). LDS-staged q/k/v
// with XOR-pre-swizzled global source (linear LDS dest), 2 threads per row.
__global__ __launch_bounds__(256) void local_attn_v3(
    const __hip_bfloat16* __restrict__ qkv, __hip_bfloat16* __restrict__ attn_out) {
  __shared__ __align__(16) ushort lds[24832];
  const int QOFF = 0;
  const int KOFF = 8192;
  const int VOFF = 8192 + 8320;

  const int tid = threadIdx.x;
  const int mb = blockIdx.x & 63;
  const int h  = blockIdx.x >> 6;
  const int rb = mb * 128;
  const int b  = rb >> 10;
  const int n0 = rb & 1023;
  const int RS = 3 * C_DIM;

#pragma unroll
  for (int i = 0; i < 4; ++i) {
    int s = i * 256 + tid;
    int r = s >> 3;
    int jg = (s & 7) ^ (r & 7);
    gload_lds16(qkv + (size_t)(rb + r) * RS + h * HD + jg * 8,
                lds + QOFF + s * 8);
  }
#pragma unroll
  for (int i = 0; i < 5; ++i) {
    int s = i * 256 + tid;
    if (s < 1040) {
      int r = s >> 3;
      int jg = (s & 7) ^ (r & 7);
      int nl = n0 + r - 1;
      nl = nl < 0 ? 0 : (nl > 1023 ? 1023 : nl);
      size_t row = (size_t)(b << 10) + nl;
      gload_lds16(qkv + row * RS + C_DIM + h * HD + jg * 8, lds + KOFF + s * 8);
      gload_lds16(qkv + row * RS + 2 * C_DIM + h * HD + jg * 8, lds + VOFF + s * 8);
    }
  }
  __syncthreads();

  const int r = tid >> 1;
  const int half = tid & 1;
  const int jbase = half * 4;
  const int n = n0 + r;

  float qf[32];
#pragma unroll
  for (int c = 0; c < 4; ++c) {
    int slot = r * 8 + ((jbase + c) ^ (r & 7));
    s16x8 v = *(const s16x8*)(lds + QOFF + slot * 8);
#pragma unroll
    for (int e = 0; e < 8; ++e) qf[c * 8 + e] = bf2f(v[e]);
  }

  float s3[3];
#pragma unroll
  for (int jj = 0; jj < 3; ++jj) {
    int krow = r + jj;
    float acc = 0.f;
#pragma unroll
    for (int c = 0; c < 4; ++c) {
      int slot = krow * 8 + ((jbase + c) ^ (krow & 7));
      s16x8 v = *(const s16x8*)(lds + KOFF + slot * 8);
#pragma unroll
      for (int e = 0; e < 8; ++e) acc += qf[c * 8 + e] * bf2f(v[e]);
    }
    acc += __shfl_xor(acc, 1);
    s3[jj] = ((unsigned)(n + jj - 1) < (unsigned)NSEQ) ? acc * 0.125f : -1e30f;
  }

  float mx = fmaxf(s3[0], fmaxf(s3[1], s3[2]));
  float p0 = __expf(s3[0] - mx);
  float p1 = __expf(s3[1] - mx);
  float p2 = __expf(s3[2] - mx);
  float inv = 1.f / (p0 + p1 + p2);
  float p[3] = {p0 * inv, p1 * inv, p2 * inv};

  float of[32] = {};
#pragma unroll
  for (int jj = 0; jj < 3; ++jj) {
    int krow = r + jj;
    float pw = p[jj];
#pragma unroll
    for (int c = 0; c < 4; ++c) {
      int slot = krow * 8 + ((jbase + c) ^ (krow & 7));
      s16x8 v = *(const s16x8*)(lds + VOFF + slot * 8);
#pragma unroll
      for (int e = 0; e < 8; ++e) of[c * 8 + e] += pw * bf2f(v[e]);
    }
  }

#pragma unroll
  for (int c = 0; c < 4; ++c) {
    s16x8 o;
#pragma unroll
    for (int e = 0; e < 8; ++e) o[e] = f2bf(of[c * 8 + e]);
    *(s16x8*)(attn_out + (size_t)(rb + r) * C_DIM + h * HD + jbase * 8 + c * 8) = o;
  }
}

extern "C" void kernel_launch(void* const* d_in, const int* in_sizes, int n_in,
                              void* d_out, int out_size, void* d_ws, size_t ws_size,
                              hipStream_t stream) {
  const float* x      = (const float*)d_in[0];  // [B,N,C]
  const float* qkv_w  = (const float*)d_in[1];  // [3C,C]
  const float* proj_w = (const float*)d_in[2];  // [C,C]
  const float* proj_b = (const float*)d_in[3];  // [C]
  float* out = (float*)d_out;                   // [B,N,C] fp32

  __hip_bfloat16* x_bf     = (__hip_bfloat16*)d_ws;
  __hip_bfloat16* qkvw_bf  = x_bf + (size_t)M_ROWS * C_DIM;
  __hip_bfloat16* projw_bf = qkvw_bf + (size_t)3 * C_DIM * C_DIM;
  __hip_bfloat16* qkv_bf   = projw_bf + (size_t)C_DIM * C_DIM;
  __hip_bfloat16* attn_bf  = qkv_bf + (size_t)M_ROWS * 3 * C_DIM;

  // 1) fused casts to bf16
  cast_all<<<1024, 256, 0, stream>>>(
      x, qkv_w, proj_w, (ushort4*)x_bf, (ushort4*)qkvw_bf, (ushort4*)projw_bf);

  // 2) qkv = x @ qkv_w^T  [8192, 1152], BN=128 -> 9x64 = 576 blocks
  gemm_db<128, true><<<dim3((3 * C_DIM) / 128, M_ROWS / 128), 256, 0, stream>>>(
      x_bf, qkvw_bf, nullptr, qkv_bf, M_ROWS, 3 * C_DIM, C_DIM);

  // 3) banded local attention (window 3): 64 row-panels x 6 heads
  local_attn_v3<<<64 * NHEADS, 256, 0, stream>>>(qkv_bf, attn_bf);

  // 4) out = attn @ proj_w^T + proj_b  [8192, 384], BN=64 -> 6x64 = 384 blocks
  gemm_db<64, false><<<dim3(C_DIM / 64, M_ROWS / 128), 256, 0, stream>>>(
      attn_bf, projw_bf, proj_b, out, M_ROWS, C_DIM, C_DIM);
}

// Round 6
// 42.751 us; speedup vs baseline: 5.3524x; 1.0288x over previous
//
#include <hip/hip_runtime.h>
#include <hip/hip_bf16.h>
#include <math.h>

#define C_DIM 384
#define NHEADS 6
#define HD 64
#define BATCH 8
#define NSEQ 1024
#define M_ROWS (BATCH * NSEQ)

typedef __attribute__((ext_vector_type(4))) float f32x4;
typedef __attribute__((ext_vector_type(8))) short s16x8;

__device__ __forceinline__ float bf2f(short u) {
  return __uint_as_float(((unsigned)(unsigned short)u) << 16);
}
__device__ __forceinline__ short f2bf(float f) {
  __hip_bfloat16 h = __float2bfloat16(f);
  return *reinterpret_cast<short*>(&h);
}
__device__ __forceinline__ s16x8 cvt8(float4 a, float4 b) {
  s16x8 r;
  r[0] = f2bf(a.x); r[1] = f2bf(a.y); r[2] = f2bf(a.z); r[3] = f2bf(a.w);
  r[4] = f2bf(b.x); r[5] = f2bf(b.y); r[6] = f2bf(b.z); r[7] = f2bf(b.w);
  return r;
}

__device__ __forceinline__ void gload_lds16(const void* g, void* l) {
  __builtin_amdgcn_global_load_lds(
      (const __attribute__((address_space(1))) unsigned int*)g,
      (__attribute__((address_space(3))) unsigned int*)l, 16, 0, 0);
}

__device__ __forceinline__ void wait_vm0() {
  asm volatile("s_waitcnt vmcnt(0)" ::: "memory");
}
__device__ __forceinline__ void lgkm0() {
  asm volatile("s_waitcnt lgkmcnt(0)" ::: "memory");
}
__device__ __forceinline__ void bar() {
  __builtin_amdgcn_sched_barrier(0);
  __builtin_amdgcn_s_barrier();
  __builtin_amdgcn_sched_barrier(0);
}

// ---------------------------------------------------------------------------
// gemm1: qkv = x @ qkv_w^T. A=x fp32 [M,K], W=qkv_w fp32 [N,K], out bf16.
// BM=128, BN=128, BK=32, 512 threads = 8 waves (2x4; wave tile 64x32).
// Both operands reg-staged fp32 -> cvt bf16 -> ds_write (fused cast).
// Double-buffered LDS; next-tile loads issued before the barrier and kept
// in flight across it (raw s_barrier, counted wait at loop top only).
// ---------------------------------------------------------------------------
__global__ __launch_bounds__(512) void gemm1_rs(
    const float* __restrict__ A, const float* __restrict__ W,
    __hip_bfloat16* __restrict__ outp, int M, int N, int K) {
  __shared__ __align__(16) __hip_bfloat16 As[2][128 * 32];
  __shared__ __align__(16) __hip_bfloat16 Bs[2][128 * 32];

  const int tid = threadIdx.x;
  const int nwg = gridDim.x * gridDim.y;           // 576, %8==0
  const int bid0 = blockIdx.y * gridDim.x + blockIdx.x;
  const int cpx = nwg >> 3;
  const int wg = (bid0 & 7) * cpx + (bid0 >> 3);   // bijective XCD swizzle
  const int bx = wg % gridDim.x;
  const int by = wg / gridDim.x;

  const int lane = tid & 63;
  const int wave = tid >> 6;          // 0..7
  const int wr = (wave >> 2) * 64;    // 0,64
  const int wc = (wave & 3) * 32;     // 0,32,64,96
  const int rowBase = by * 128;
  const int colBase = bx * 128;
  const int l16 = lane & 15;
  const int lk8 = (lane >> 4) * 8;
  const int lr4 = (lane >> 4) * 4;

  // staging: thread covers row sr (0..127), 8 consecutive cols at sc
  const int sr = tid >> 2;
  const int sc = (tid & 3) * 8;
  const float* aSrc = A + (size_t)(rowBase + sr) * K + sc;
  const float* bSrc = W + (size_t)(colBase + sr) * K + sc;

  f32x4 acc[4][2] = {};
  float4 aL[2], bL[2];

  auto loadRegs = [&](int kt) {
    const float4* ap = (const float4*)(aSrc + kt * 32);
    aL[0] = ap[0]; aL[1] = ap[1];
    const float4* bp = (const float4*)(bSrc + kt * 32);
    bL[0] = bp[0]; bL[1] = bp[1];
  };

  loadRegs(0);
  const int nkt = K >> 5;  // 12
  for (int kt = 0; kt < nkt; ++kt) {
    const int cur = kt & 1;
    wait_vm0();
    __builtin_amdgcn_sched_barrier(0);
    *(s16x8*)&As[cur][sr * 32 + sc] = cvt8(aL[0], aL[1]);
    *(s16x8*)&Bs[cur][sr * 32 + sc] = cvt8(bL[0], bL[1]);
    if (kt + 1 < nkt) loadRegs(kt + 1);  // in flight across barrier + MFMA
    lgkm0();
    bar();

    s16x8 af[4], bfr[2];
#pragma unroll
    for (int m = 0; m < 4; ++m)
      af[m] = *(const s16x8*)(&As[cur][(wr + m * 16 + l16) * 32 + lk8]);
#pragma unroll
    for (int n = 0; n < 2; ++n)
      bfr[n] = *(const s16x8*)(&Bs[cur][(wc + n * 16 + l16) * 32 + lk8]);
#pragma unroll
    for (int m = 0; m < 4; ++m)
#pragma unroll
      for (int n = 0; n < 2; ++n)
        acc[m][n] = __builtin_amdgcn_mfma_f32_16x16x32_bf16(
            af[m], bfr[n], acc[m][n], 0, 0, 0);
    bar();
  }

#pragma unroll
  for (int m = 0; m < 4; ++m) {
    int rb = rowBase + wr + m * 16 + lr4;
#pragma unroll
    for (int n = 0; n < 2; ++n) {
      int cb = colBase + wc + n * 16 + l16;
#pragma unroll
      for (int j = 0; j < 4; ++j)
        outp[(size_t)(rb + j) * N + cb] = __float2bfloat16(acc[m][n][j]);
    }
  }
}

// ---------------------------------------------------------------------------
// gemm2: out = attn @ proj_w^T + b. A=attn bf16 (global_load_lds staged),
// W=proj_w fp32 (reg-staged + cvt), out fp32. BM=128, BN=64, 256 threads.
// ---------------------------------------------------------------------------
__global__ __launch_bounds__(256) void gemm2_mix(
    const __hip_bfloat16* __restrict__ A, const float* __restrict__ W,
    const float* __restrict__ bias, float* __restrict__ outp,
    int M, int N, int K) {
  __shared__ __align__(16) __hip_bfloat16 As[2][128 * 32];
  __shared__ __align__(16) __hip_bfloat16 Bs[2][64 * 32];

  const int tid = threadIdx.x;
  const int nwg = gridDim.x * gridDim.y;           // 384, %8==0
  const int bid0 = blockIdx.y * gridDim.x + blockIdx.x;
  const int cpx = nwg >> 3;
  const int wg = (bid0 & 7) * cpx + (bid0 >> 3);
  const int bx = wg % gridDim.x;
  const int by = wg / gridDim.x;

  const int lane = tid & 63;
  const int wave = tid >> 6;        // 0..3
  const int wr = (wave >> 1) * 64;  // 0,64
  const int wc = (wave & 1) * 32;   // 0,32
  const int rowBase = by * 128;
  const int colBase = bx * 64;
  const int l16 = lane & 15;
  const int lk8 = (lane >> 4) * 8;
  const int lr4 = (lane >> 4) * 4;

  const int sr = tid >> 2;          // 0..63 (B rows)
  const int sc = (tid & 3) * 8;
  const float* bSrc = W + (size_t)(colBase + sr) * K + sc;

  f32x4 acc[4][2] = {};
  float4 bL[2];

  auto stageA = [&](int kt, int buf) {
#pragma unroll
    for (int i = 0; i < 2; ++i) {
      int c = tid + i * 256;
      int r = c >> 2, cc = (c & 3) * 8;
      gload_lds16(A + (size_t)(rowBase + r) * K + kt * 32 + cc, &As[buf][c * 8]);
    }
  };
  auto loadB = [&](int kt) {
    const float4* bp = (const float4*)(bSrc + kt * 32);
    bL[0] = bp[0]; bL[1] = bp[1];
  };

  stageA(0, 0);
  loadB(0);
  const int nkt = K >> 5;  // 12
  for (int kt = 0; kt < nkt; ++kt) {
    const int cur = kt & 1;
    wait_vm0();                       // A(kt) in LDS, B(kt) in regs
    __builtin_amdgcn_sched_barrier(0);
    *(s16x8*)&Bs[cur][sr * 32 + sc] = cvt8(bL[0], bL[1]);
    if (kt + 1 < nkt) {
      stageA(kt + 1, cur ^ 1);        // safe: all waves done reading cur^1
      loadB(kt + 1);
    }
    lgkm0();
    bar();

    s16x8 af[4], bfr[2];
#pragma unroll
    for (int m = 0; m < 4; ++m)
      af[m] = *(const s16x8*)(&As[cur][(wr + m * 16 + l16) * 32 + lk8]);
#pragma unroll
    for (int n = 0; n < 2; ++n)
      bfr[n] = *(const s16x8*)(&Bs[cur][(wc + n * 16 + l16) * 32 + lk8]);
#pragma unroll
    for (int m = 0; m < 4; ++m)
#pragma unroll
      for (int n = 0; n < 2; ++n)
        acc[m][n] = __builtin_amdgcn_mfma_f32_16x16x32_bf16(
            af[m], bfr[n], acc[m][n], 0, 0, 0);
    bar();
  }

#pragma unroll
  for (int m = 0; m < 4; ++m) {
    int rb = rowBase + wr + m * 16 + lr4;
#pragma unroll
    for (int n = 0; n < 2; ++n) {
      int cb = colBase + wc + n * 16 + l16;
      float bv = bias[cb];
#pragma unroll
      for (int j = 0; j < 4; ++j)
        outp[(size_t)(rb + j) * N + cb] = acc[m][n][j] + bv;
    }
  }
}

// ---------------------------------------------------------------------------
// Local attention: one block per (128-row panel, head). LDS-staged q/k/v with
// XOR-pre-swizzled global source (linear LDS dest), 2 threads per row.
// ---------------------------------------------------------------------------
__global__ __launch_bounds__(256) void local_attn_v3(
    const __hip_bfloat16* __restrict__ qkv, __hip_bfloat16* __restrict__ attn_out) {
  __shared__ __align__(16) ushort lds[24832];
  const int QOFF = 0;
  const int KOFF = 8192;
  const int VOFF = 8192 + 8320;

  const int tid = threadIdx.x;
  const int mb = blockIdx.x & 63;
  const int h  = blockIdx.x >> 6;
  const int rb = mb * 128;
  const int b  = rb >> 10;
  const int n0 = rb & 1023;
  const int RS = 3 * C_DIM;

#pragma unroll
  for (int i = 0; i < 4; ++i) {
    int s = i * 256 + tid;
    int r = s >> 3;
    int jg = (s & 7) ^ (r & 7);
    gload_lds16(qkv + (size_t)(rb + r) * RS + h * HD + jg * 8,
                lds + QOFF + s * 8);
  }
#pragma unroll
  for (int i = 0; i < 5; ++i) {
    int s = i * 256 + tid;
    if (s < 1040) {
      int r = s >> 3;
      int jg = (s & 7) ^ (r & 7);
      int nl = n0 + r - 1;
      nl = nl < 0 ? 0 : (nl > 1023 ? 1023 : nl);
      size_t row = (size_t)(b << 10) + nl;
      gload_lds16(qkv + row * RS + C_DIM + h * HD + jg * 8, lds + KOFF + s * 8);
      gload_lds16(qkv + row * RS + 2 * C_DIM + h * HD + jg * 8, lds + VOFF + s * 8);
    }
  }
  __syncthreads();

  const int r = tid >> 1;
  const int half = tid & 1;
  const int jbase = half * 4;
  const int n = n0 + r;

  float qf[32];
#pragma unroll
  for (int c = 0; c < 4; ++c) {
    int slot = r * 8 + ((jbase + c) ^ (r & 7));
    s16x8 v = *(const s16x8*)(lds + QOFF + slot * 8);
#pragma unroll
    for (int e = 0; e < 8; ++e) qf[c * 8 + e] = bf2f(v[e]);
  }

  float s3[3];
#pragma unroll
  for (int jj = 0; jj < 3; ++jj) {
    int krow = r + jj;
    float acc = 0.f;
#pragma unroll
    for (int c = 0; c < 4; ++c) {
      int slot = krow * 8 + ((jbase + c) ^ (krow & 7));
      s16x8 v = *(const s16x8*)(lds + KOFF + slot * 8);
#pragma unroll
      for (int e = 0; e < 8; ++e) acc += qf[c * 8 + e] * bf2f(v[e]);
    }
    acc += __shfl_xor(acc, 1);
    s3[jj] = ((unsigned)(n + jj - 1) < (unsigned)NSEQ) ? acc * 0.125f : -1e30f;
  }

  float mx = fmaxf(s3[0], fmaxf(s3[1], s3[2]));
  float p0 = __expf(s3[0] - mx);
  float p1 = __expf(s3[1] - mx);
  float p2 = __expf(s3[2] - mx);
  float inv = 1.f / (p0 + p1 + p2);
  float p[3] = {p0 * inv, p1 * inv, p2 * inv};

  float of[32] = {};
#pragma unroll
  for (int jj = 0; jj < 3; ++jj) {
    int krow = r + jj;
    float pw = p[jj];
#pragma unroll
    for (int c = 0; c < 4; ++c) {
      int slot = krow * 8 + ((jbase + c) ^ (krow & 7));
      s16x8 v = *(const s16x8*)(lds + VOFF + slot * 8);
#pragma unroll
      for (int e = 0; e < 8; ++e) of[c * 8 + e] += pw * bf2f(v[e]);
    }
  }

#pragma unroll
  for (int c = 0; c < 4; ++c) {
    s16x8 o;
#pragma unroll
    for (int e = 0; e < 8; ++e) o[e] = f2bf(of[c * 8 + e]);
    *(s16x8*)(attn_out + (size_t)(rb + r) * C_DIM + h * HD + jbase * 8 + c * 8) = o;
  }
}

extern "C" void kernel_launch(void* const* d_in, const int* in_sizes, int n_in,
                              void* d_out, int out_size, void* d_ws, size_t ws_size,
                              hipStream_t stream) {
  const float* x      = (const float*)d_in[0];  // [B,N,C]
  const float* qkv_w  = (const float*)d_in[1];  // [3C,C]
  const float* proj_w = (const float*)d_in[2];  // [C,C]
  const float* proj_b = (const float*)d_in[3];  // [C]
  float* out = (float*)d_out;                   // [B,N,C] fp32

  __hip_bfloat16* qkv_bf  = (__hip_bfloat16*)d_ws;                 // [8192,1152]
  __hip_bfloat16* attn_bf = qkv_bf + (size_t)M_ROWS * 3 * C_DIM;   // [8192,384]

  // 1) qkv = x @ qkv_w^T (fused fp32->bf16 cast in staging), 9x64 = 576 blocks
  gemm1_rs<<<dim3(9, 64), 512, 0, stream>>>(
      x, qkv_w, qkv_bf, M_ROWS, 3 * C_DIM, C_DIM);

  // 2) banded local attention (window 3): 64 row-panels x 6 heads
  local_attn_v3<<<64 * NHEADS, 256, 0, stream>>>(qkv_bf, attn_bf);

  // 3) out = attn @ proj_w^T + proj_b (fused W cast), 6x64 = 384 blocks
  gemm2_mix<<<dim3(6, 64), 256, 0, stream>>>(
      attn_bf, proj_w, proj_b, out, M_ROWS, C_DIM, C_DIM);
}